// Round 2
// baseline (575.592 us; speedup 1.0000x reference)
//
#include <hip/hip_runtime.h>
#include <stdint.h>

#define Bn 4
#define Sn 2048
#define Dn 1024
#define Hn 16
#define DKn 64

typedef __bf16 bf16x8 __attribute__((ext_vector_type(8)));
typedef float f32x4 __attribute__((ext_vector_type(4)));
typedef unsigned short u16;

union ABFrag { bf16x8 v; uint4 u; };
union V8 { u16 us[8]; uint4 u; };

__device__ __forceinline__ u16 f2bf(float f) {
  union { float f; uint32_t u; } a; a.f = f;
  return (u16)((a.u + 0x7fffu + ((a.u >> 16) & 1u)) >> 16);
}

__device__ __forceinline__ void gload16(const void* g, void* l) {
  __builtin_amdgcn_global_load_lds((const __attribute__((address_space(1))) unsigned int*)g,
                                   (__attribute__((address_space(3))) unsigned int*)l, 16, 0, 0);
}

__device__ __forceinline__ f32x4 zero4() { f32x4 z; z[0]=0.f; z[1]=0.f; z[2]=0.f; z[3]=0.f; return z; }

// ---------------- prep kernels ----------------

__global__ void conv_bf16(const float* __restrict__ src, u16* __restrict__ dst, int n4) {
  int i = blockIdx.x * 256 + threadIdx.x;
  if (i < n4) {
    float4 v = ((const float4*)src)[i];
    V8 o;
    o.us[0] = f2bf(v.x); o.us[1] = f2bf(v.y); o.us[2] = f2bf(v.z); o.us[3] = f2bf(v.w);
    ((uint2*)dst)[i] = make_uint2(o.u.x, o.u.y);
  }
}

// Wcatt[w][n][d] = Wsrc_w[h][d][dk],  n = h*64+dk   (i.e. pre-transposed [N][K])
__global__ void prep_wqkv(const float* __restrict__ Wq, const float* __restrict__ Wk,
                          const float* __restrict__ Wv, u16* __restrict__ out) {
  int i = blockIdx.x * 256 + threadIdx.x;   // 3*1024*1024 threads
  int d = i & 1023;
  int n = (i >> 10) & 1023;
  int w = i >> 20;
  const float* src = (w == 0) ? Wq : (w == 1) ? Wk : Wv;
  int h = n >> 6, dk = n & 63;
  out[i] = f2bf(src[(h * Dn + d) * DKn + dk]);
}

// Wot[n][d] = Wo[d][n]
__global__ void prep_wo(const float* __restrict__ Wo, u16* __restrict__ out) {
  int i = blockIdx.x * 256 + threadIdx.x;   // 1024*1024
  int d = i & 1023, n = i >> 10;
  out[i] = f2bf(Wo[d * Dn + n]);
}

// mask dtype hedge: if mask uploaded as 1-byte bools, 32-bit words will whp exceed 1.
__global__ void mask_detect(const uint32_t* __restrict__ mw, int* __restrict__ flag) {
  int t = threadIdx.x;
  uint32_t acc = 0;
  for (int j = 0; j < 4; ++j) acc |= (mw[t * 4 + j] > 1u) ? 1u : 0u;
  unsigned long long bal = __ballot(acc != 0);
  __shared__ int s[4];
  if ((t & 63) == 0) s[t >> 6] = (bal != 0ull) ? 1 : 0;
  __syncthreads();
  if (t == 0) *flag = s[0] | s[1] | s[2] | s[3];
}

__global__ void mask_unpack(const void* __restrict__ mraw, const int* __restrict__ flag,
                            uchar4* __restrict__ m8, int n4) {
  int i = blockIdx.x * 256 + threadIdx.x;
  if (i >= n4) return;
  uchar4 o;
  if (*flag) {  // byte-bool source
    uchar4 v = ((const uchar4*)mraw)[i];
    o.x = v.x ? 1 : 0; o.y = v.y ? 1 : 0; o.z = v.z ? 1 : 0; o.w = v.w ? 1 : 0;
  } else {      // int32 source
    uint4 v = ((const uint4*)mraw)[i];
    o.x = v.x ? 1 : 0; o.y = v.y ? 1 : 0; o.z = v.z ? 1 : 0; o.w = v.w ? 1 : 0;
  }
  m8[i] = o;
}

// vh[bh][s][dk] -> vt[bh][dk][s]  (bf16, 64x64 LDS tile, swizzled)
__global__ void transpose_v(const u16* __restrict__ vh, u16* __restrict__ vt) {
  __shared__ char lds[64 * 128];
  int tid = threadIdx.x;
  int bh = blockIdx.y, s0 = blockIdx.x * 64;
  const char* src = (const char*)(vh + ((size_t)bh * Sn + s0) * DKn);
  #pragma unroll
  for (int si = 0; si < 2; ++si) {
    int c = si * 256 + tid, r = c >> 3, cb = c & 7;
    uint4 v = *(const uint4*)(src + r * 128 + cb * 16);
    *(uint4*)(lds + r * 128 + ((cb ^ (r & 7)) << 4)) = v;
  }
  __syncthreads();
  #pragma unroll
  for (int si = 0; si < 2; ++si) {
    int c = si * 256 + tid, dkr = c >> 3, sb = c & 7;
    V8 t;
    #pragma unroll
    for (int j = 0; j < 8; ++j) {
      int s = sb * 8 + j;
      t.us[j] = *(const u16*)(lds + s * 128 + ((dkr * 2) ^ ((s & 7) << 4)));
    }
    *(uint4*)(vt + ((size_t)bh * DKn + dkr) * Sn + s0 + sb * 8) = t.u;
  }
}

// ---------------- GEMM (128x128 tile, BK=64, 4 waves) ----------------
// MODE 0: merged QKV projection, N=3072 (A selected per n-block), bf16 out [b,h,s,dk], +bias, Q scaled by log2e/8
// MODE 1: output projection, N=1024, fp32 out [m][n], +bias
template<int MODE>
__launch_bounds__(256)
__global__ void gemm_kernel(const u16* __restrict__ Aq, const u16* __restrict__ Ak,
                            const u16* __restrict__ Av, const u16* __restrict__ Bm,
                            const float* __restrict__ bq, const float* __restrict__ bk,
                            const float* __restrict__ bv,
                            u16* __restrict__ Oq, u16* __restrict__ Ok, u16* __restrict__ Ov,
                            float* __restrict__ Of) {
  __shared__ char lds[32768];
  char* Al = lds;
  char* Bl = lds + 16384;
  const int tid = threadIdx.x, w = tid >> 6, lane = tid & 63;
  const int n0 = blockIdx.x * 128, m0 = blockIdx.y * 128;
  int which = 0;
  const u16* A = Aq;
  if (MODE == 0) { which = n0 >> 10; A = (which == 0) ? Aq : (which == 1) ? Ak : Av; }

  f32x4 acc[2][8];
  #pragma unroll
  for (int i = 0; i < 2; ++i)
    #pragma unroll
    for (int j = 0; j < 8; ++j) acc[i][j] = zero4();

  for (int kt = 0; kt < 16; ++kt) {
    __syncthreads();
    #pragma unroll
    for (int si = 0; si < 4; ++si) {
      int c = si * 256 + tid, r = c >> 3, cb = c & 7;
      gload16((const char*)A + (((size_t)(m0 + r)) << 11) + (size_t)(kt * 128) + ((cb ^ (r & 7)) << 4),
              Al + si * 4096 + w * 1024);
    }
    #pragma unroll
    for (int si = 0; si < 4; ++si) {
      int c = si * 256 + tid, r = c >> 3, cb = c & 7;
      gload16((const char*)Bm + (((size_t)(n0 + r)) << 11) + (size_t)(kt * 128) + ((cb ^ (r & 7)) << 4),
              Bl + si * 4096 + w * 1024);
    }
    __syncthreads();
    #pragma unroll
    for (int kk = 0; kk < 2; ++kk) {
      ABFrag a0, a1;
      {
        int row = w * 32 + (lane & 15);
        int ch = (lane >> 4) + kk * 4;
        a0.u = *(const uint4*)(Al + row * 128 + ((ch ^ (row & 7)) << 4));
        row += 16;
        a1.u = *(const uint4*)(Al + row * 128 + ((ch ^ (row & 7)) << 4));
      }
      #pragma unroll
      for (int nn = 0; nn < 8; ++nn) {
        int row = nn * 16 + (lane & 15);
        int ch = (lane >> 4) + kk * 4;
        ABFrag bb; bb.u = *(const uint4*)(Bl + row * 128 + ((ch ^ (row & 7)) << 4));
        acc[0][nn] = __builtin_amdgcn_mfma_f32_16x16x32_bf16(a0.v, bb.v, acc[0][nn], 0, 0, 0);
        acc[1][nn] = __builtin_amdgcn_mfma_f32_16x16x32_bf16(a1.v, bb.v, acc[1][nn], 0, 0, 0);
      }
    }
  }

  if (MODE == 0) {
    const float esc = (which == 0) ? 0.18033688011112042f : 1.0f;  // log2(e)/8 folded into Q
    const float* bias = (which == 0) ? bq : (which == 1) ? bk : bv;
    u16* O = (which == 0) ? Oq : (which == 1) ? Ok : Ov;
    #pragma unroll
    for (int nn = 0; nn < 8; ++nn) {
      int ng = (n0 & 1023) + nn * 16 + (lane & 15);
      int h = ng >> 6, dk = ng & 63;
      float bsv = bias[ng];
      #pragma unroll
      for (int mm = 0; mm < 2; ++mm) {
        #pragma unroll
        for (int r = 0; r < 4; ++r) {
          int mg = m0 + w * 32 + mm * 16 + (lane >> 4) * 4 + r;
          int b = mg >> 11, s = mg & 2047;
          O[(((size_t)(b * Hn + h)) * Sn + s) * DKn + dk] = f2bf((acc[mm][nn][r] + bsv) * esc);
        }
      }
    }
  } else {
    #pragma unroll
    for (int nn = 0; nn < 8; ++nn) {
      int ng = n0 + nn * 16 + (lane & 15);
      float bsv = bq[ng];
      #pragma unroll
      for (int mm = 0; mm < 2; ++mm) {
        #pragma unroll
        for (int r = 0; r < 4; ++r) {
          int mg = m0 + w * 32 + mm * 16 + (lane >> 4) * 4 + r;
          Of[(size_t)mg * 1024 + ng] = acc[mm][nn][r] + bsv;
        }
      }
    }
  }
}

// ---------------- flash attention ----------------
// grid (32 q-tiles, 64 bh); 4 waves x 16 q-rows; KV tiles of 64; online softmax in exp2 domain
// (Q pre-scaled by log2e/8 at projection; masked score = -1e-6*log2e).
__launch_bounds__(256)
__global__ void flash_attn(const u16* __restrict__ qh, const u16* __restrict__ kh,
                           const u16* __restrict__ vt, const unsigned char* __restrict__ m8,
                           u16* __restrict__ o) {
  __shared__ char lds[8192 * 2 + 4 * 2048];   // K 8KB | Vt 8KB | P 4x2KB
  char* Klds = lds;
  char* Vlds = lds + 8192;
  const int tid = threadIdx.x, w = tid >> 6, lane = tid & 63;
  char* Plds = lds + 16384 + w * 2048;
  const int bh = blockIdx.y, b = bh >> 4, h = bh & 15;
  const int q0 = blockIdx.x * 64;
  const int qr = q0 + w * 16;

  // Q fragments (A operand), rows = lane&15
  ABFrag aq[2];
  {
    const char* qrow = (const char*)(qh + ((size_t)bh * Sn + qr + (lane & 15)) * DKn);
    aq[0].u = *(const uint4*)(qrow + (lane >> 4) * 16);
    aq[1].u = *(const uint4*)(qrow + 64 + (lane >> 4) * 16);
  }

  float mrun[4], ssum[4];
  f32x4 oacc[4];
  #pragma unroll
  for (int r = 0; r < 4; ++r) { mrun[r] = -__builtin_inff(); ssum[r] = 0.f; }
  #pragma unroll
  for (int nn = 0; nn < 4; ++nn) oacc[nn] = zero4();

  const char* kbase = (const char*)(kh + (size_t)bh * Sn * DKn);
  const char* vbase = (const char*)(vt + (size_t)bh * DKn * Sn);
  const unsigned char* mrow0 = m8 + (size_t)b * Sn * Sn;
  const int rowg = qr + (lane >> 4) * 4;

  for (int kt = 0; kt < Sn / 64; ++kt) {
    __syncthreads();
    #pragma unroll
    for (int si = 0; si < 2; ++si) {
      int c = si * 256 + tid, r = c >> 3, cb = c & 7;
      gload16(kbase + (size_t)(kt * 64 + r) * 128 + ((cb ^ (r & 7)) << 4),
              Klds + si * 4096 + w * 1024);
    }
    #pragma unroll
    for (int si = 0; si < 2; ++si) {
      int c = si * 256 + tid, r = c >> 3, cb = c & 7;
      gload16(vbase + (size_t)r * (Sn * 2) + (size_t)(kt * 128) + ((cb ^ (r & 7)) << 4),
              Vlds + si * 4096 + w * 1024);
    }
    __syncthreads();

    // QK^T
    f32x4 sacc[4];
    #pragma unroll
    for (int nn = 0; nn < 4; ++nn) sacc[nn] = zero4();
    #pragma unroll
    for (int kk = 0; kk < 2; ++kk) {
      #pragma unroll
      for (int nn = 0; nn < 4; ++nn) {
        int row = nn * 16 + (lane & 15);
        int ch = (lane >> 4) + kk * 4;
        ABFrag bk_; bk_.u = *(const uint4*)(Klds + row * 128 + ((ch ^ (row & 7)) << 4));
        sacc[nn] = __builtin_amdgcn_mfma_f32_16x16x32_bf16(aq[kk].v, bk_.v, sacc[nn], 0, 0, 0);
      }
    }

    // mask + online softmax (exp2 domain)
    float p[4][4];
    #pragma unroll
    for (int r = 0; r < 4; ++r) {
      const unsigned char* mr = mrow0 + (size_t)(rowg + r) * Sn + kt * 64 + (lane & 15);
      float mx = -__builtin_inff();
      #pragma unroll
      for (int nn = 0; nn < 4; ++nn) {
        float v = mr[nn * 16] ? sacc[nn][r] : -1.4426950408889634e-6f;
        p[nn][r] = v;
        mx = fmaxf(mx, v);
      }
      #pragma unroll
      for (int off = 1; off < 16; off <<= 1) mx = fmaxf(mx, __shfl_xor(mx, off, 16));
      float mnew = fmaxf(mrun[r], mx);
      float scl = exp2f(mrun[r] - mnew);
      mrun[r] = mnew;
      float rs = 0.f;
      #pragma unroll
      for (int nn = 0; nn < 4; ++nn) { float e = exp2f(p[nn][r] - mnew); p[nn][r] = e; rs += e; }
      #pragma unroll
      for (int off = 1; off < 16; off <<= 1) rs += __shfl_xor(rs, off, 16);
      ssum[r] = ssum[r] * scl + rs;
      #pragma unroll
      for (int nn = 0; nn < 4; ++nn) oacc[nn][r] *= scl;
    }

    // P -> LDS (bf16, swizzled) so it can be read back as the PV A-fragment
    #pragma unroll
    for (int r = 0; r < 4; ++r) {
      int row = (lane >> 4) * 4 + r;
      #pragma unroll
      for (int nn = 0; nn < 4; ++nn) {
        int colb = (nn * 16 + (lane & 15)) * 2;
        *(u16*)(Plds + row * 128 + (colb ^ ((row & 7) << 4))) = f2bf(p[nn][r]);
      }
    }

    // PV
    #pragma unroll
    for (int kk = 0; kk < 2; ++kk) {
      ABFrag pa;
      {
        int row = lane & 15;
        int chb = kk * 64 + (lane >> 4) * 16;
        pa.u = *(const uint4*)(Plds + row * 128 + (chb ^ ((row & 7) << 4)));
      }
      #pragma unroll
      for (int nn = 0; nn < 4; ++nn) {
        int row = nn * 16 + (lane & 15);
        int ch = (lane >> 4) + kk * 4;
        ABFrag vb; vb.u = *(const uint4*)(Vlds + row * 128 + ((ch ^ (row & 7)) << 4));
        oacc[nn] = __builtin_amdgcn_mfma_f32_16x16x32_bf16(pa.v, vb.v, oacc[nn], 0, 0, 0);
      }
    }
  }

  // finalize: divide by softmax sum, write concat-head layout [b][s][h*64+dk]
  #pragma unroll
  for (int r = 0; r < 4; ++r) {
    int sg = qr + (lane >> 4) * 4 + r;
    float inv = 1.f / ssum[r];
    #pragma unroll
    for (int nn = 0; nn < 4; ++nn) {
      int col = h * 64 + nn * 16 + (lane & 15);
      o[((size_t)(b * Sn) + sg) * Dn + col] = f2bf(oacc[nn][r] * inv);
    }
  }
}

// ---------------- host ----------------

extern "C" void kernel_launch(void* const* d_in, const int* in_sizes, int n_in,
                              void* d_out, int out_size, void* d_ws, size_t ws_size,
                              hipStream_t stream) {
  (void)in_sizes; (void)n_in; (void)out_size; (void)ws_size;
  const float* q  = (const float*)d_in[0];
  const float* k  = (const float*)d_in[1];
  const float* v  = (const float*)d_in[2];
  const void*  mask = d_in[3];
  const float* Wq = (const float*)d_in[4];
  const float* bq = (const float*)d_in[5];
  const float* Wk = (const float*)d_in[6];
  const float* bk = (const float*)d_in[7];
  const float* Wv = (const float*)d_in[8];
  const float* bv = (const float*)d_in[9];
  const float* Wo = (const float*)d_in[10];
  const float* bo = (const float*)d_in[11];
  float* out = (float*)d_out;

  char* ws = (char*)d_ws;
  const size_t SZ = (size_t)8192 * 1024 * 2;      // 16.78 MB
  u16* qbf   = (u16*)(ws);                        // later reused as o_concat
  u16* kbf   = (u16*)(ws + SZ);                   // later reused as vt
  u16* vbf   = (u16*)(ws + 2 * SZ);               // later reused as mask8
  u16* Wcatt = (u16*)(ws + 3 * SZ);               // 6 MB
  u16* Wot   = (u16*)(ws + 3 * SZ + 6291456);     // 2 MB
  u16* qhp   = (u16*)(ws + 3 * SZ + 8388608);
  u16* khp   = (u16*)((char*)qhp + SZ);
  u16* vhp   = (u16*)((char*)khp + SZ);
  int* flag  = (int*)((char*)vhp + SZ);

  conv_bf16<<<8192, 256, 0, stream>>>(q, qbf, 2097152);
  conv_bf16<<<8192, 256, 0, stream>>>(k, kbf, 2097152);
  conv_bf16<<<8192, 256, 0, stream>>>(v, vbf, 2097152);
  prep_wqkv<<<12288, 256, 0, stream>>>(Wq, Wk, Wv, Wcatt);
  prep_wo<<<4096, 256, 0, stream>>>(Wo, Wot);

  gemm_kernel<0><<<dim3(24, 64), 256, 0, stream>>>(qbf, kbf, vbf, Wcatt, bq, bk, bv,
                                                   qhp, khp, vhp, nullptr);

  mask_detect<<<1, 256, 0, stream>>>((const uint32_t*)mask, flag);
  unsigned char* m8 = (unsigned char*)vbf;        // vbf dead after gemm<0>
  mask_unpack<<<16384, 256, 0, stream>>>(mask, flag, (uchar4*)m8, 4194304);

  u16* vtb = kbf;                                 // kbf dead after gemm<0>
  transpose_v<<<dim3(32, 64), 256, 0, stream>>>(vhp, vtb);

  u16* oc = qbf;                                  // qbf dead after gemm<0>
  flash_attn<<<dim3(32, 64), 256, 0, stream>>>(qhp, khp, vtb, m8, oc);

  gemm_kernel<1><<<dim3(8, 64), 256, 0, stream>>>(oc, nullptr, nullptr, Wot, bo,
                                                  nullptr, nullptr, nullptr,
                                                  nullptr, nullptr, out);
}